// Round 8
// baseline (897.368 us; speedup 1.0000x reference)
//
#include <hip/hip_runtime.h>
#include <stdint.h>

typedef __attribute__((ext_vector_type(8))) short short8;
typedef __attribute__((ext_vector_type(4))) float f32x4;

struct us4 { unsigned short x, y, z, w; };

__device__ __forceinline__ float b2f(unsigned short u){
  union { unsigned int i; float f; } x; x.i = ((unsigned int)u) << 16; return x.f;
}
__device__ __forceinline__ unsigned short f2b(float f){
  union { float f; unsigned int i; } x; x.f = f;
  unsigned int i = x.i;
  unsigned int r = (i + 0x7FFFu + ((i >> 16) & 1u)) >> 16;
  return (unsigned short)r;
}
__device__ __forceinline__ float sane(float v){
  return fminf(fmaxf(v, -1e30f), 1e30f);
}
// clamp logit: NaN -> -60, range +-60 (exp-safe; softmax invariant to shift)
__device__ __forceinline__ float lclamp(float v){
  return fminf(fmaxf(v, -60.f), 60.f);
}
__device__ __forceinline__ float ldin(const void* p, size_t i, int f32){
  return f32 ? ((const float*)p)[i] : b2f(((const unsigned short*)p)[i]);
}

// ---------------- dtype discriminator ----------------
__global__ void k_flag(const unsigned short* __restrict__ xu, int* __restrict__ flag){
  __shared__ int cnt;
  if (threadIdx.x == 0) cnt = 0;
  __syncthreads();
  unsigned u = xu[2 * threadIdx.x];
  int e = (u >> 7) & 0xFF;
  if (e >= 97 && e <= 132) atomicAdd(&cnt, 1);
  __syncthreads();
  if (threadIdx.x == 0) flag[0] = (cnt >= 192) ? 0 : 1;   // 0=bf16, 1=fp32
}

// ---------------- x -> bf16 canonical copy (vectorized) ----------------
__global__ void k_cvt(const void* __restrict__ xin, unsigned short* __restrict__ xb,
                      int n4, const int* __restrict__ flagp){
  int f32 = *flagp;
  int i = blockIdx.x * 256 + threadIdx.x;
  if (i < n4){
    if (f32){
      float4 v = ((const float4*)xin)[i];
      us4 o = { f2b(v.x), f2b(v.y), f2b(v.z), f2b(v.w) };
      ((us4*)xb)[i] = o;
    } else {
      ((us4*)xb)[i] = ((const us4*)xin)[i];
    }
  }
}

// ---------------- CSR build (parallel scan) ----------------
__global__ void k_deg(const int* __restrict__ ei, int E, int N, int* __restrict__ deg){
  int e = blockIdx.x * 256 + threadIdx.x;
  if (e < E){
    unsigned d = (unsigned)ei[E + e];
    if (d < (unsigned)N) atomicAdd(&deg[d], 1);
  }
}

__global__ void k_bsum(const int* __restrict__ deg, int N, int* __restrict__ bsum){
  int b = blockIdx.x, t = threadIdx.x;
  int i0 = b * 1024 + t * 4;
  int s = 0;
  if (i0 + 4 <= N){
    int4 v = *(const int4*)&deg[i0];
    s = v.x + v.y + v.z + v.w;
  } else {
    #pragma unroll
    for (int j = 0; j < 4; ++j){ int i = i0 + j; if (i < N) s += deg[i]; }
  }
  #pragma unroll
  for (int off = 32; off; off >>= 1) s += __shfl_xor(s, off);
  __shared__ int ws[4];
  if ((t & 63) == 0) ws[t >> 6] = s;
  __syncthreads();
  if (t == 0) bsum[b] = ws[0] + ws[1] + ws[2] + ws[3];
}

__global__ void k_bscan(const int* __restrict__ bsum, int nb,
                        int* __restrict__ boff, int* __restrict__ rowptr, int N){
  int t = threadIdx.x;
  if (nb <= 64){
    int v = (t < nb) ? bsum[t] : 0;
    int inc = v;
    #pragma unroll
    for (int off = 1; off < 64; off <<= 1){
      int u = __shfl_up(inc, off);
      if (t >= off) inc += u;
    }
    if (t < nb) boff[t] = inc - v;
    if (t == 63) rowptr[N] = inc;
  } else {
    if (t == 0){
      int run = 0;
      for (int i = 0; i < nb; ++i){ boff[i] = run; run += bsum[i]; }
      rowptr[N] = run;
    }
  }
}

__global__ void k_rowptr(const int* __restrict__ deg, const int* __restrict__ boff,
                         int N, int* __restrict__ rowptr, int* __restrict__ cursor){
  int b = blockIdx.x, t = threadIdx.x;
  int i0 = b * 1024 + t * 4;
  int d0 = 0, d1 = 0, d2 = 0, d3 = 0;
  if (i0 + 4 <= N){
    int4 v = *(const int4*)&deg[i0];
    d0 = v.x; d1 = v.y; d2 = v.z; d3 = v.w;
  } else {
    if (i0     < N) d0 = deg[i0];
    if (i0 + 1 < N) d1 = deg[i0 + 1];
    if (i0 + 2 < N) d2 = deg[i0 + 2];
    if (i0 + 3 < N) d3 = deg[i0 + 3];
  }
  int s = d0 + d1 + d2 + d3;
  int lane = t & 63, w = t >> 6;
  int inc = s;
  #pragma unroll
  for (int off = 1; off < 64; off <<= 1){
    int u = __shfl_up(inc, off);
    if (lane >= off) inc += u;
  }
  int wex = inc - s;
  __shared__ int wtot[4];
  if (lane == 63) wtot[w] = inc;
  __syncthreads();
  int cross = 0;
  for (int i = 0; i < w; ++i) cross += wtot[i];
  int basev = boff[b] + cross + wex;
  int r0 = basev, r1 = basev + d0, r2 = r1 + d1, r3 = r2 + d2;
  if (i0 + 4 <= N){
    int4 o = { r0, r1, r2, r3 };
    *(int4*)&rowptr[i0] = o;
    *(int4*)&cursor[i0] = o;
  } else {
    if (i0     < N){ rowptr[i0]   = r0; cursor[i0]   = r0; }
    if (i0 + 1 < N){ rowptr[i0+1] = r1; cursor[i0+1] = r1; }
    if (i0 + 2 < N){ rowptr[i0+2] = r2; cursor[i0+2] = r2; }
    if (i0 + 3 < N){ rowptr[i0+3] = r3; cursor[i0+3] = r3; }
  }
}

__global__ void k_scatter(const int* __restrict__ ei, int E, int N,
                          int* __restrict__ cursor, int* __restrict__ srcs){
  int e = blockIdx.x * 256 + threadIdx.x;
  if (e < E){
    unsigned d = (unsigned)ei[E + e];
    if (d < (unsigned)N){
      int pos = atomicAdd(&cursor[d], 1);
      if ((unsigned)pos < (unsigned)E){
        unsigned s = (unsigned)ei[e];
        srcs[pos] = (s < (unsigned)N) ? (int)s : 0;
      }
    }
  }
}

// ---------------- weight pack: WT[cg][k] = W_mat[k][c] (bf16), bias as float ----------------
__global__ void k_pack(const void* __restrict__ Wq, const void* __restrict__ bq,
                       const void* __restrict__ Wk, const void* __restrict__ bk,
                       const void* __restrict__ Wv, const void* __restrict__ bv,
                       const void* __restrict__ Ws, const void* __restrict__ bs,
                       unsigned short* __restrict__ WT, float* __restrict__ bias,
                       int Mq, int Ms, int K, const int* __restrict__ flagp){
  int f32 = *flagp;
  int cg = blockIdx.x;
  int k  = threadIdx.x;
  int mat, c, mc;
  if (cg < 3 * Mq){ mat = cg / Mq; c = cg % Mq; mc = Mq; }
  else if (cg < 3 * Mq + Ms){ mat = 3; c = cg - 3 * Mq; mc = Ms; }
  else { mat = 4; c = 0; mc = 1; }
  const void* W = (mat==0)?Wq:(mat==1)?Wk:(mat==2)?Wv:(mat==3)?Ws:(const void*)0;
  WT[(size_t)cg * K + k] = (mat < 4) ? f2b(ldin(W, (size_t)k * mc + c, f32)) : (unsigned short)0;
  if (k == 0){
    const void* B = (mat==0)?bq:(mat==1)?bk:(mat==2)?bv:(mat==3)?bs:(const void*)0;
    bias[cg] = (mat < 4) ? ldin(B, c, f32) : 0.f;
  }
}

// ---------------- GEMM: split-output (per-section stride), coalesced LDS epilogue ----------------
__global__ __launch_bounds__(256) void k_gemm(const unsigned short* __restrict__ A,
                                              const unsigned short* __restrict__ WT,
                                              const float* __restrict__ bias,
                                              unsigned short* __restrict__ B0,
                                              unsigned short* __restrict__ B1,
                                              unsigned short* __restrict__ B2,
                                              unsigned short* __restrict__ B3,
                                              int N, int Mout, int secshift,
                                              int st0, int st1, int st2, int st3){
  __shared__ __align__(16) unsigned short Alds[64][264];
  __shared__ __align__(16) unsigned short Clds[32][276];
  int tid = threadIdx.x, wid = tid >> 6, lane = tid & 63;
  int l15 = lane & 15, l4 = lane >> 4;
  int row0 = blockIdx.x * 64;
  {
    int srow = tid >> 2, sc4 = tid & 3;
    int ar = row0 + srow; if (ar >= N) ar = N - 1;
    const unsigned short* Ap = A + (size_t)ar * 256;
    #pragma unroll
    for (int i = 0; i < 8; ++i){
      int col = (sc4 + 4 * i) * 8;
      *(short8*)&Alds[srow][col] = *(const short8*)&Ap[col];
    }
  }
  __syncthreads();
  int secw = 1 << secshift;
  int strow = tid >> 3, stchunk = tid & 7;
  for (int cb = wid * 64; cb < Mout; cb += 256){
    f32x4 acc[4][4] = {};
    #pragma unroll
    for (int k0 = 0; k0 < 256; k0 += 32){
      short8 a0 = *(const short8*)&Alds[l15     ][k0 + l4*8];
      short8 a1 = *(const short8*)&Alds[16 + l15][k0 + l4*8];
      short8 a2 = *(const short8*)&Alds[32 + l15][k0 + l4*8];
      short8 a3 = *(const short8*)&Alds[48 + l15][k0 + l4*8];
      const unsigned short* wb = WT + (size_t)(cb + l15) * 256 + k0 + l4*8;
      short8 b0 = *(const short8*)(wb);
      short8 b1 = *(const short8*)(wb + 16*256);
      short8 b2 = *(const short8*)(wb + 32*256);
      short8 b3 = *(const short8*)(wb + 48*256);
      acc[0][0] = __builtin_amdgcn_mfma_f32_16x16x32_bf16(a0, b0, acc[0][0], 0,0,0);
      acc[0][1] = __builtin_amdgcn_mfma_f32_16x16x32_bf16(a0, b1, acc[0][1], 0,0,0);
      acc[0][2] = __builtin_amdgcn_mfma_f32_16x16x32_bf16(a0, b2, acc[0][2], 0,0,0);
      acc[0][3] = __builtin_amdgcn_mfma_f32_16x16x32_bf16(a0, b3, acc[0][3], 0,0,0);
      acc[1][0] = __builtin_amdgcn_mfma_f32_16x16x32_bf16(a1, b0, acc[1][0], 0,0,0);
      acc[1][1] = __builtin_amdgcn_mfma_f32_16x16x32_bf16(a1, b1, acc[1][1], 0,0,0);
      acc[1][2] = __builtin_amdgcn_mfma_f32_16x16x32_bf16(a1, b2, acc[1][2], 0,0,0);
      acc[1][3] = __builtin_amdgcn_mfma_f32_16x16x32_bf16(a1, b3, acc[1][3], 0,0,0);
      acc[2][0] = __builtin_amdgcn_mfma_f32_16x16x32_bf16(a2, b0, acc[2][0], 0,0,0);
      acc[2][1] = __builtin_amdgcn_mfma_f32_16x16x32_bf16(a2, b1, acc[2][1], 0,0,0);
      acc[2][2] = __builtin_amdgcn_mfma_f32_16x16x32_bf16(a2, b2, acc[2][2], 0,0,0);
      acc[2][3] = __builtin_amdgcn_mfma_f32_16x16x32_bf16(a2, b3, acc[2][3], 0,0,0);
      acc[3][0] = __builtin_amdgcn_mfma_f32_16x16x32_bf16(a3, b0, acc[3][0], 0,0,0);
      acc[3][1] = __builtin_amdgcn_mfma_f32_16x16x32_bf16(a3, b1, acc[3][1], 0,0,0);
      acc[3][2] = __builtin_amdgcn_mfma_f32_16x16x32_bf16(a3, b2, acc[3][2], 0,0,0);
      acc[3][3] = __builtin_amdgcn_mfma_f32_16x16x32_bf16(a3, b3, acc[3][3], 0,0,0);
    }
    int gb = cb - wid * 64;
    #pragma unroll
    for (int ph = 0; ph < 2; ++ph){
      #pragma unroll
      for (int rt2 = 0; rt2 < 2; ++rt2){
        int rt = ph*2 + rt2;
        #pragma unroll
        for (int ct = 0; ct < 4; ++ct){
          float bv = bias[cb + ct*16 + l15];
          #pragma unroll
          for (int r = 0; r < 4; ++r)
            Clds[rt2*16 + l4*4 + r][wid*64 + ct*16 + l15] = f2b(acc[rt][ct][r] + bv);
        }
      }
      __syncthreads();
      int grow = row0 + ph*32 + strow;
      if (grow < N){
        int g0 = gb + stchunk * 32;
        int mat = g0 >> secshift;
        int cc  = g0 & (secw - 1);
        unsigned short* Bp = (mat==0)?B0:(mat==1)?B1:(mat==2)?B2:B3;
        int stw = (mat==0)?st0:(mat==1)?st1:(mat==2)?st2:st3;
        unsigned short* dst = Bp + (size_t)grow * stw + cc;
        const unsigned short* srcp = &Clds[strow][stchunk * 32];
        #pragma unroll
        for (int j = 0; j < 4; ++j)
          *(short8*)(dst + j*8) = *(const short8*)(srcp + j*8);
      }
      __syncthreads();
    }
  }
}

// ---------------- fused node kernel, layers 1&2: one wave per node, kv-packed ----------------
// kv row = [k 0..255 | v 256..511]. One 1KB wave-load per edge (16B/lane).
// Lanes 0-31 carry k channels 8l.., lanes 32-63 carry v channels 8(l-32)..
__global__ __launch_bounds__(256) void k_attn(const unsigned short* __restrict__ qb,
                                              const unsigned short* __restrict__ kv,
                                              const unsigned short* __restrict__ xb,
                                              const int* __restrict__ rowptr,
                                              const int* __restrict__ srcs,
                                              const void* __restrict__ Wb,
                                              const void* __restrict__ lng,
                                              const void* __restrict__ lnb,
                                              unsigned short* __restrict__ hout,
                                              int N, int E, const int* __restrict__ flagp){
  int f32 = *flagp;
  int tid = threadIdx.x, w = tid >> 6, l = tid & 63;
  int n = blockIdx.x * 4 + w;
  if (n >= N) return;
  int m = l & 31;                 // channel-group index (8 ch per lane)
  size_t base = (size_t)n * 256;
  // q channels 8m..8m+7 (meaningful for lower half; harmless mirror for upper)
  float qf[8];
  {
    short8 qv8 = *(const short8*)&qb[base + m*8];
    #pragma unroll
    for (int j = 0; j < 8; ++j) qf[j] = b2f((unsigned short)qv8[j]);
  }
  int e0 = rowptr[n], e1 = rowptr[n+1];
  if (e0 < 0) e0 = 0;
  if (e1 > E) e1 = E;
  const float scale = 0.17677669529663687f;  // 1/sqrt(32)
  float ss = 0.f;
  float o[8] = {0,0,0,0,0,0,0,0};
  int e = e0;
  for (; e + 2 <= e1; e += 2){
    unsigned s0 = (unsigned)srcs[e];   if (s0 >= (unsigned)N) s0 = 0;
    unsigned s1 = (unsigned)srcs[e+1]; if (s1 >= (unsigned)N) s1 = 0;
    short8 cA = *(const short8*)&kv[(size_t)s0*512 + l*8];
    short8 cB = *(const short8*)&kv[(size_t)s1*512 + l*8];
    float fA[8], fB[8];
    #pragma unroll
    for (int j = 0; j < 8; ++j){ fA[j] = b2f((unsigned short)cA[j]); fB[j] = b2f((unsigned short)cB[j]); }
    float pA = qf[0]*fA[0] + qf[1]*fA[1] + qf[2]*fA[2] + qf[3]*fA[3]
             + qf[4]*fA[4] + qf[5]*fA[5] + qf[6]*fA[6] + qf[7]*fA[7];
    float pB = qf[0]*fB[0] + qf[1]*fB[1] + qf[2]*fB[2] + qf[3]*fB[3]
             + qf[4]*fB[4] + qf[5]*fB[5] + qf[6]*fB[6] + qf[7]*fB[7];
    pA += __shfl_xor(pA, 1); pA += __shfl_xor(pA, 2);
    pB += __shfl_xor(pB, 1); pB += __shfl_xor(pB, 2);
    float wA = __expf(lclamp(pA * scale));
    float wB = __expf(lclamp(pB * scale));
    ss += wA + wB;
    float wvA = __shfl_xor(wA, 32);   // upper lanes get their head's weight
    float wvB = __shfl_xor(wB, 32);
    #pragma unroll
    for (int j = 0; j < 8; ++j) o[j] += wvA * fA[j] + wvB * fB[j];
  }
  for (; e < e1; ++e){
    unsigned s = (unsigned)srcs[e]; if (s >= (unsigned)N) s = 0;
    short8 cA = *(const short8*)&kv[(size_t)s*512 + l*8];
    float fA[8];
    #pragma unroll
    for (int j = 0; j < 8; ++j) fA[j] = b2f((unsigned short)cA[j]);
    float pA = qf[0]*fA[0] + qf[1]*fA[1] + qf[2]*fA[2] + qf[3]*fA[3]
             + qf[4]*fA[4] + qf[5]*fA[5] + qf[6]*fA[6] + qf[7]*fA[7];
    pA += __shfl_xor(pA, 1); pA += __shfl_xor(pA, 2);
    float wA = __expf(lclamp(pA * scale));
    ss += wA;
    float wvA = __shfl_xor(wA, 32);
    #pragma unroll
    for (int j = 0; j < 8; ++j) o[j] += wvA * fA[j];
  }
  // upper lanes: normalize with their head's denominator
  float ssu = __shfl_xor(ss, 32);
  float sinv = 1.f / (ssu + 1e-16f);
  #pragma unroll
  for (int j = 0; j < 8; ++j) o[j] = sane(o[j] * sinv);
  // epilogue in upper half (lanes 32-63), channels c0 = 8m..8m+7
  int c0 = m * 8;
  float xf[8];
  {
    short8 xv8 = *(const short8*)&xb[base + c0];
    #pragma unroll
    for (int j = 0; j < 8; ++j) xf[j] = sane(b2f((unsigned short)xv8[j]));
  }
  float d = 0.f;
  #pragma unroll
  for (int j = 0; j < 8; ++j){
    int c = c0 + j;
    d += o[j]*ldin(Wb, c, f32) + xf[j]*ldin(Wb, 256+c, f32) + (o[j]-xf[j])*ldin(Wb, 512+c, f32);
  }
  d += __shfl_xor(d, 1); d += __shfl_xor(d, 2); d += __shfl_xor(d, 4);
  d += __shfl_xor(d, 8); d += __shfl_xor(d, 16);
  float beta = 1.f / (1.f + __expf(-d));
  float r[8], sm = 0.f;
  #pragma unroll
  for (int j = 0; j < 8; ++j){ r[j] = beta*xf[j] + (1.f-beta)*o[j]; sm += r[j]; }
  sm += __shfl_xor(sm, 1); sm += __shfl_xor(sm, 2); sm += __shfl_xor(sm, 4);
  sm += __shfl_xor(sm, 8); sm += __shfl_xor(sm, 16);
  float mu = sm * (1.f/256.f);
  float vv = 0.f;
  #pragma unroll
  for (int j = 0; j < 8; ++j){ float dj = r[j]-mu; vv += dj*dj; }
  vv += __shfl_xor(vv, 1); vv += __shfl_xor(vv, 2); vv += __shfl_xor(vv, 4);
  vv += __shfl_xor(vv, 8); vv += __shfl_xor(vv, 16);
  float rs = rsqrtf(vv * (1.f/256.f) + 1e-5f);
  if (l >= 32){
    short8 outv;
    #pragma unroll
    for (int j = 0; j < 8; ++j){
      int c = c0 + j;
      float y = (r[j]-mu)*rs*ldin(lng, c, f32) + ldin(lnb, c, f32);
      outv[j] = (short)f2b(fmaxf(y, 0.f));
    }
    *(short8*)&hout[base + c0] = outv;
  }
}

// ---------------- fused node kernel, layer 3: one wave per node, kv-packed ----------------
// kv3 row = [k 0..63 | v 64..127] (256 B). One wave-load covers 4 edges (16 lanes each).
// Within 16 lanes: t<8 -> head t's full k (8 ch); t>=8 -> head (t-8)'s full v.
__global__ __launch_bounds__(256) void k_final(const unsigned short* __restrict__ q3,
                                               const unsigned short* __restrict__ kv3,
                                               const unsigned short* __restrict__ x3,
                                               const int* __restrict__ rowptr,
                                               const int* __restrict__ srcs,
                                               const void* __restrict__ Wb,
                                               void* __restrict__ outp,
                                               int N, int E, const int* __restrict__ flagp){
  int f32 = *flagp;
  int tid = threadIdx.x, w = tid >> 6, l = tid & 63;
  int n = blockIdx.x * 4 + w;
  if (n >= N) return;
  int es = l >> 4, t = l & 15;
  size_t base = (size_t)n * 64;
  float qf[8];
  {
    short8 qv8 = *(const short8*)&q3[base + (t & 7)*8];
    #pragma unroll
    for (int j = 0; j < 8; ++j) qf[j] = b2f((unsigned short)qv8[j]);
  }
  int e0 = rowptr[n], e1 = rowptr[n+1];
  if (e0 < 0) e0 = 0;
  if (e1 > E) e1 = E;
  int deg = e1 - e0;
  const float scale = 0.35355339059327373f;  // 1/sqrt(8)
  float ss = 0.f;
  float o[8] = {0,0,0,0,0,0,0,0};
  for (int ei = es; ei < deg; ei += 4){
    unsigned s = (unsigned)srcs[e0 + ei]; if (s >= (unsigned)N) s = 0;
    short8 cA = *(const short8*)&kv3[(size_t)s*128 + t*8];
    float fA[8];
    #pragma unroll
    for (int j = 0; j < 8; ++j) fA[j] = b2f((unsigned short)cA[j]);
    float p = qf[0]*fA[0] + qf[1]*fA[1] + qf[2]*fA[2] + qf[3]*fA[3]
            + qf[4]*fA[4] + qf[5]*fA[5] + qf[6]*fA[6] + qf[7]*fA[7];
    float wA = __expf(lclamp(p * scale));
    ss += wA;
    float wv = __shfl_xor(wA, 8);   // v lanes get their head's weight
    #pragma unroll
    for (int j = 0; j < 8; ++j) o[j] += wv * fA[j];
  }
  // merge es groups
  ss += __shfl_xor(ss, 16); ss += __shfl_xor(ss, 32);
  #pragma unroll
  for (int j = 0; j < 8; ++j){ o[j] += __shfl_xor(o[j], 16); o[j] += __shfl_xor(o[j], 32); }
  // v lanes normalize by their head's denominator
  float ssu = __shfl_xor(ss, 8);
  float sinv = 1.f / (ssu + 1e-16f);
  #pragma unroll
  for (int j = 0; j < 8; ++j) o[j] = sane(o[j] * sinv);
  // mean over heads: reduce across t-8 (bits 0..2) within v lanes
  #pragma unroll
  for (int j = 0; j < 8; ++j){
    o[j] += __shfl_xor(o[j], 1); o[j] += __shfl_xor(o[j], 2); o[j] += __shfl_xor(o[j], 4);
    o[j] *= 0.125f;
  }
  float xf[8];
  {
    short8 xv8 = *(const short8*)&x3[base];   // skip channels 0..7
    #pragma unroll
    for (int j = 0; j < 8; ++j) xf[j] = sane(b2f((unsigned short)xv8[j]));
  }
  float d = 0.f;
  #pragma unroll
  for (int j = 0; j < 8; ++j)
    d += o[j]*ldin(Wb, j, f32) + xf[j]*ldin(Wb, 8+j, f32) + (o[j]-xf[j])*ldin(Wb, 16+j, f32);
  float beta = 1.f / (1.f + __expf(-d));
  if (l == 8){
    if (f32){
      float* op = (float*)outp + (size_t)n*8;
      #pragma unroll
      for (int j = 0; j < 8; ++j) op[j] = beta*xf[j] + (1.f-beta)*o[j];
    } else {
      short8 ov;
      #pragma unroll
      for (int j = 0; j < 8; ++j) ov[j] = (short)f2b(beta*xf[j] + (1.f-beta)*o[j]);
      *(short8*)((unsigned short*)outp + (size_t)n*8) = ov;
    }
  }
}

extern "C" void kernel_launch(void* const* d_in, const int* in_sizes, int n_in,
                              void* d_out, int out_size, void* d_ws, size_t ws_size,
                              hipStream_t stream){
  const int* ei = (const int*)d_in[1];
  const int N = in_sizes[0] / 256;
  const int E = in_sizes[1] / 2;

  char* wsp = (char*)d_ws;
  size_t off = 0;
  auto alloc = [&](size_t b) -> void* {
    void* p = wsp + off; off = (off + b + 255) & ~(size_t)255; return p;
  };
  unsigned short* WT1  = (unsigned short*)alloc((size_t)1024*256*2);
  unsigned short* WT2  = (unsigned short*)alloc((size_t)1024*256*2);
  unsigned short* WT3  = (unsigned short*)alloc((size_t)256*256*2);
  float* bias1 = (float*)alloc(1024*4);
  float* bias2 = (float*)alloc(1024*4);
  float* bias3 = (float*)alloc(256*4);
  int* flag   = (int*)alloc(256);
  int* deg    = (int*)alloc((size_t)N*4);
  int* rowptr = (int*)alloc((size_t)(N+1)*4);
  int* cursor = (int*)alloc((size_t)N*4);
  int* bsum   = (int*)alloc(1024*4);
  int* boff   = (int*)alloc(1024*4);
  int* srcs   = (int*)alloc((size_t)E*4);
  unsigned short* xbf = (unsigned short*)alloc((size_t)N*256*2);
  unsigned short* qb  = (unsigned short*)alloc((size_t)N*256*2);
  unsigned short* kv  = (unsigned short*)alloc((size_t)N*512*2);
  unsigned short* xb  = (unsigned short*)alloc((size_t)N*256*2);
  unsigned short* hbuf= (unsigned short*)alloc((size_t)N*256*2);
  unsigned short* q3  = qb;      // layer-3 aliases (then-free)
  unsigned short* kv3 = kv;
  unsigned short* x3  = xb;
  (void)ws_size; (void)n_in; (void)out_size;

  // dtype flag + canonical bf16 x
  k_flag<<<1, 256, 0, stream>>>((const unsigned short*)d_in[0], flag);
  int n4 = (N * 256) / 4;
  k_cvt<<<(n4 + 255) / 256, 256, 0, stream>>>(d_in[0], xbf, n4, flag);

  // CSR build (dst-sorted), parallel scan
  hipMemsetAsync(deg, 0, (size_t)N*4, stream);
  int eb = (E + 255) / 256;
  int nbk = (N + 1023) / 1024;
  k_deg<<<eb, 256, 0, stream>>>(ei, E, N, deg);
  k_bsum<<<nbk, 256, 0, stream>>>(deg, N, bsum);
  k_bscan<<<1, 64, 0, stream>>>(bsum, nbk, boff, rowptr, N);
  k_rowptr<<<nbk, 256, 0, stream>>>(deg, boff, N, rowptr, cursor);
  k_scatter<<<eb, 256, 0, stream>>>(ei, E, N, cursor, srcs);

  // pack transposed fused weights + biases
  k_pack<<<1024, 256, 0, stream>>>(d_in[2],  d_in[3],  d_in[4],  d_in[5],  d_in[6],  d_in[7],  d_in[8],  d_in[9],  WT1, bias1, 256, 256, 256, flag);
  k_pack<<<1024, 256, 0, stream>>>(d_in[11], d_in[12], d_in[13], d_in[14], d_in[15], d_in[16], d_in[17], d_in[18], WT2, bias2, 256, 256, 256, flag);
  k_pack<<< 256, 256, 0, stream>>>(d_in[20], d_in[21], d_in[22], d_in[23], d_in[24], d_in[25], d_in[26], d_in[27], WT3, bias3,  64,   8, 256, flag);

  int rb = (N + 63) / 64;
  int nb = (N + 3) / 4;
  // layer 1: sections q|k|v|x -> qb, kv(+0), kv(+256), xb
  k_gemm<<<rb, 256, 0, stream>>>(xbf, WT1, bias1, qb, kv, kv + 256, xb, N, 1024, 8, 256, 512, 512, 256);
  k_attn<<<nb, 256, 0, stream>>>(qb, kv, xb, rowptr, srcs, d_in[10], d_in[29], d_in[30], hbuf, N, E, flag);
  // layer 2
  k_gemm<<<rb, 256, 0, stream>>>(hbuf, WT2, bias2, qb, kv, kv + 256, xb, N, 1024, 8, 256, 512, 512, 256);
  k_attn<<<nb, 256, 0, stream>>>(qb, kv, xb, rowptr, srcs, d_in[19], d_in[31], d_in[32], hbuf, N, E, flag);
  // layer 3: sections q|k|v|x (64 each) -> q3, kv3(+0), kv3(+64), x3
  k_gemm<<<rb, 256, 0, stream>>>(hbuf, WT3, bias3, q3, kv3, kv3 + 64, x3, N, 256, 6, 64, 128, 128, 64);
  k_final<<<nb, 256, 0, stream>>>(q3, kv3, x3, rowptr, srcs, d_in[28], d_out, N, E, flag);
}

// Round 9
// 702.692 us; speedup vs baseline: 1.2770x; 1.2770x over previous
//
#include <hip/hip_runtime.h>
#include <stdint.h>

typedef __attribute__((ext_vector_type(8))) short short8;
typedef __attribute__((ext_vector_type(4))) float f32x4;

struct us4 { unsigned short x, y, z, w; };

__device__ __forceinline__ float b2f(unsigned short u){
  union { unsigned int i; float f; } x; x.i = ((unsigned int)u) << 16; return x.f;
}
__device__ __forceinline__ unsigned short f2b(float f){
  union { float f; unsigned int i; } x; x.f = f;
  unsigned int i = x.i;
  unsigned int r = (i + 0x7FFFu + ((i >> 16) & 1u)) >> 16;
  return (unsigned short)r;
}
__device__ __forceinline__ float sane(float v){
  return fminf(fmaxf(v, -1e30f), 1e30f);
}
// clamp logit: NaN -> -60, range +-60 (exp-safe; softmax invariant to shift)
__device__ __forceinline__ float lclamp(float v){
  return fminf(fmaxf(v, -60.f), 60.f);
}
__device__ __forceinline__ float ldin(const void* p, size_t i, int f32){
  return f32 ? ((const float*)p)[i] : b2f(((const unsigned short*)p)[i]);
}

// ---------------- dtype discriminator ----------------
__global__ void k_flag(const unsigned short* __restrict__ xu, int* __restrict__ flag){
  __shared__ int cnt;
  if (threadIdx.x == 0) cnt = 0;
  __syncthreads();
  unsigned u = xu[2 * threadIdx.x];
  int e = (u >> 7) & 0xFF;
  if (e >= 97 && e <= 132) atomicAdd(&cnt, 1);
  __syncthreads();
  if (threadIdx.x == 0) flag[0] = (cnt >= 192) ? 0 : 1;   // 0=bf16, 1=fp32
}

// ---------------- x -> bf16 canonical copy (vectorized) ----------------
__global__ void k_cvt(const void* __restrict__ xin, unsigned short* __restrict__ xb,
                      int n4, const int* __restrict__ flagp){
  int f32 = *flagp;
  int i = blockIdx.x * 256 + threadIdx.x;
  if (i < n4){
    if (f32){
      float4 v = ((const float4*)xin)[i];
      us4 o = { f2b(v.x), f2b(v.y), f2b(v.z), f2b(v.w) };
      ((us4*)xb)[i] = o;
    } else {
      ((us4*)xb)[i] = ((const us4*)xin)[i];
    }
  }
}

// ---------------- CSR build (parallel scan) ----------------
__global__ void k_deg(const int* __restrict__ ei, int E, int N, int* __restrict__ deg){
  int e = blockIdx.x * 256 + threadIdx.x;
  if (e < E){
    unsigned d = (unsigned)ei[E + e];
    if (d < (unsigned)N) atomicAdd(&deg[d], 1);
  }
}

__global__ void k_bsum(const int* __restrict__ deg, int N, int* __restrict__ bsum){
  int b = blockIdx.x, t = threadIdx.x;
  int i0 = b * 1024 + t * 4;
  int s = 0;
  if (i0 + 4 <= N){
    int4 v = *(const int4*)&deg[i0];
    s = v.x + v.y + v.z + v.w;
  } else {
    #pragma unroll
    for (int j = 0; j < 4; ++j){ int i = i0 + j; if (i < N) s += deg[i]; }
  }
  #pragma unroll
  for (int off = 32; off; off >>= 1) s += __shfl_xor(s, off);
  __shared__ int ws[4];
  if ((t & 63) == 0) ws[t >> 6] = s;
  __syncthreads();
  if (t == 0) bsum[b] = ws[0] + ws[1] + ws[2] + ws[3];
}

__global__ void k_bscan(const int* __restrict__ bsum, int nb,
                        int* __restrict__ boff, int* __restrict__ rowptr, int N){
  int t = threadIdx.x;
  if (nb <= 64){
    int v = (t < nb) ? bsum[t] : 0;
    int inc = v;
    #pragma unroll
    for (int off = 1; off < 64; off <<= 1){
      int u = __shfl_up(inc, off);
      if (t >= off) inc += u;
    }
    if (t < nb) boff[t] = inc - v;
    if (t == 63) rowptr[N] = inc;
  } else {
    if (t == 0){
      int run = 0;
      for (int i = 0; i < nb; ++i){ boff[i] = run; run += bsum[i]; }
      rowptr[N] = run;
    }
  }
}

__global__ void k_rowptr(const int* __restrict__ deg, const int* __restrict__ boff,
                         int N, int* __restrict__ rowptr, int* __restrict__ cursor){
  int b = blockIdx.x, t = threadIdx.x;
  int i0 = b * 1024 + t * 4;
  int d0 = 0, d1 = 0, d2 = 0, d3 = 0;
  if (i0 + 4 <= N){
    int4 v = *(const int4*)&deg[i0];
    d0 = v.x; d1 = v.y; d2 = v.z; d3 = v.w;
  } else {
    if (i0     < N) d0 = deg[i0];
    if (i0 + 1 < N) d1 = deg[i0 + 1];
    if (i0 + 2 < N) d2 = deg[i0 + 2];
    if (i0 + 3 < N) d3 = deg[i0 + 3];
  }
  int s = d0 + d1 + d2 + d3;
  int lane = t & 63, w = t >> 6;
  int inc = s;
  #pragma unroll
  for (int off = 1; off < 64; off <<= 1){
    int u = __shfl_up(inc, off);
    if (lane >= off) inc += u;
  }
  int wex = inc - s;
  __shared__ int wtot[4];
  if (lane == 63) wtot[w] = inc;
  __syncthreads();
  int cross = 0;
  for (int i = 0; i < w; ++i) cross += wtot[i];
  int basev = boff[b] + cross + wex;
  int r0 = basev, r1 = basev + d0, r2 = r1 + d1, r3 = r2 + d2;
  if (i0 + 4 <= N){
    int4 o = { r0, r1, r2, r3 };
    *(int4*)&rowptr[i0] = o;
    *(int4*)&cursor[i0] = o;
  } else {
    if (i0     < N){ rowptr[i0]   = r0; cursor[i0]   = r0; }
    if (i0 + 1 < N){ rowptr[i0+1] = r1; cursor[i0+1] = r1; }
    if (i0 + 2 < N){ rowptr[i0+2] = r2; cursor[i0+2] = r2; }
    if (i0 + 3 < N){ rowptr[i0+3] = r3; cursor[i0+3] = r3; }
  }
}

__global__ void k_scatter(const int* __restrict__ ei, int E, int N,
                          int* __restrict__ cursor, int* __restrict__ srcs){
  int e = blockIdx.x * 256 + threadIdx.x;
  if (e < E){
    unsigned d = (unsigned)ei[E + e];
    if (d < (unsigned)N){
      int pos = atomicAdd(&cursor[d], 1);
      if ((unsigned)pos < (unsigned)E){
        unsigned s = (unsigned)ei[e];
        srcs[pos] = (s < (unsigned)N) ? (int)s : 0;
      }
    }
  }
}

// ---------------- weight pack: WT[cg][k] = W_mat[k][c] (bf16), bias as float ----------------
__global__ void k_pack(const void* __restrict__ Wq, const void* __restrict__ bq,
                       const void* __restrict__ Wk, const void* __restrict__ bk,
                       const void* __restrict__ Wv, const void* __restrict__ bv,
                       const void* __restrict__ Ws, const void* __restrict__ bs,
                       unsigned short* __restrict__ WT, float* __restrict__ bias,
                       int Mq, int Ms, int K, const int* __restrict__ flagp){
  int f32 = *flagp;
  int cg = blockIdx.x;
  int k  = threadIdx.x;
  int mat, c, mc;
  if (cg < 3 * Mq){ mat = cg / Mq; c = cg % Mq; mc = Mq; }
  else if (cg < 3 * Mq + Ms){ mat = 3; c = cg - 3 * Mq; mc = Ms; }
  else { mat = 4; c = 0; mc = 1; }
  const void* W = (mat==0)?Wq:(mat==1)?Wk:(mat==2)?Wv:(mat==3)?Ws:(const void*)0;
  WT[(size_t)cg * K + k] = (mat < 4) ? f2b(ldin(W, (size_t)k * mc + c, f32)) : (unsigned short)0;
  if (k == 0){
    const void* B = (mat==0)?bq:(mat==1)?bk:(mat==2)?bv:(mat==3)?bs:(const void*)0;
    bias[cg] = (mat < 4) ? ldin(B, c, f32) : 0.f;
  }
}

// ---------------- GEMM: split-output (per-section stride), coalesced LDS epilogue ----------------
__global__ __launch_bounds__(256) void k_gemm(const unsigned short* __restrict__ A,
                                              const unsigned short* __restrict__ WT,
                                              const float* __restrict__ bias,
                                              unsigned short* __restrict__ B0,
                                              unsigned short* __restrict__ B1,
                                              unsigned short* __restrict__ B2,
                                              unsigned short* __restrict__ B3,
                                              int N, int Mout, int secshift,
                                              int st0, int st1, int st2, int st3){
  __shared__ __align__(16) unsigned short Alds[64][264];
  __shared__ __align__(16) unsigned short Clds[32][276];
  int tid = threadIdx.x, wid = tid >> 6, lane = tid & 63;
  int l15 = lane & 15, l4 = lane >> 4;
  int row0 = blockIdx.x * 64;
  {
    int srow = tid >> 2, sc4 = tid & 3;
    int ar = row0 + srow; if (ar >= N) ar = N - 1;
    const unsigned short* Ap = A + (size_t)ar * 256;
    #pragma unroll
    for (int i = 0; i < 8; ++i){
      int col = (sc4 + 4 * i) * 8;
      *(short8*)&Alds[srow][col] = *(const short8*)&Ap[col];
    }
  }
  __syncthreads();
  int secw = 1 << secshift;
  int strow = tid >> 3, stchunk = tid & 7;
  for (int cb = wid * 64; cb < Mout; cb += 256){
    f32x4 acc[4][4] = {};
    #pragma unroll
    for (int k0 = 0; k0 < 256; k0 += 32){
      short8 a0 = *(const short8*)&Alds[l15     ][k0 + l4*8];
      short8 a1 = *(const short8*)&Alds[16 + l15][k0 + l4*8];
      short8 a2 = *(const short8*)&Alds[32 + l15][k0 + l4*8];
      short8 a3 = *(const short8*)&Alds[48 + l15][k0 + l4*8];
      const unsigned short* wb = WT + (size_t)(cb + l15) * 256 + k0 + l4*8;
      short8 b0 = *(const short8*)(wb);
      short8 b1 = *(const short8*)(wb + 16*256);
      short8 b2 = *(const short8*)(wb + 32*256);
      short8 b3 = *(const short8*)(wb + 48*256);
      acc[0][0] = __builtin_amdgcn_mfma_f32_16x16x32_bf16(a0, b0, acc[0][0], 0,0,0);
      acc[0][1] = __builtin_amdgcn_mfma_f32_16x16x32_bf16(a0, b1, acc[0][1], 0,0,0);
      acc[0][2] = __builtin_amdgcn_mfma_f32_16x16x32_bf16(a0, b2, acc[0][2], 0,0,0);
      acc[0][3] = __builtin_amdgcn_mfma_f32_16x16x32_bf16(a0, b3, acc[0][3], 0,0,0);
      acc[1][0] = __builtin_amdgcn_mfma_f32_16x16x32_bf16(a1, b0, acc[1][0], 0,0,0);
      acc[1][1] = __builtin_amdgcn_mfma_f32_16x16x32_bf16(a1, b1, acc[1][1], 0,0,0);
      acc[1][2] = __builtin_amdgcn_mfma_f32_16x16x32_bf16(a1, b2, acc[1][2], 0,0,0);
      acc[1][3] = __builtin_amdgcn_mfma_f32_16x16x32_bf16(a1, b3, acc[1][3], 0,0,0);
      acc[2][0] = __builtin_amdgcn_mfma_f32_16x16x32_bf16(a2, b0, acc[2][0], 0,0,0);
      acc[2][1] = __builtin_amdgcn_mfma_f32_16x16x32_bf16(a2, b1, acc[2][1], 0,0,0);
      acc[2][2] = __builtin_amdgcn_mfma_f32_16x16x32_bf16(a2, b2, acc[2][2], 0,0,0);
      acc[2][3] = __builtin_amdgcn_mfma_f32_16x16x32_bf16(a2, b3, acc[2][3], 0,0,0);
      acc[3][0] = __builtin_amdgcn_mfma_f32_16x16x32_bf16(a3, b0, acc[3][0], 0,0,0);
      acc[3][1] = __builtin_amdgcn_mfma_f32_16x16x32_bf16(a3, b1, acc[3][1], 0,0,0);
      acc[3][2] = __builtin_amdgcn_mfma_f32_16x16x32_bf16(a3, b2, acc[3][2], 0,0,0);
      acc[3][3] = __builtin_amdgcn_mfma_f32_16x16x32_bf16(a3, b3, acc[3][3], 0,0,0);
    }
    int gb = cb - wid * 64;
    #pragma unroll
    for (int ph = 0; ph < 2; ++ph){
      #pragma unroll
      for (int rt2 = 0; rt2 < 2; ++rt2){
        int rt = ph*2 + rt2;
        #pragma unroll
        for (int ct = 0; ct < 4; ++ct){
          float bv = bias[cb + ct*16 + l15];
          #pragma unroll
          for (int r = 0; r < 4; ++r)
            Clds[rt2*16 + l4*4 + r][wid*64 + ct*16 + l15] = f2b(acc[rt][ct][r] + bv);
        }
      }
      __syncthreads();
      int grow = row0 + ph*32 + strow;
      if (grow < N){
        int g0 = gb + stchunk * 32;
        int mat = g0 >> secshift;
        int cc  = g0 & (secw - 1);
        unsigned short* Bp = (mat==0)?B0:(mat==1)?B1:(mat==2)?B2:B3;
        int stw = (mat==0)?st0:(mat==1)?st1:(mat==2)?st2:st3;
        unsigned short* dst = Bp + (size_t)grow * stw + cc;
        const unsigned short* srcp = &Clds[strow][stchunk * 32];
        #pragma unroll
        for (int j = 0; j < 4; ++j)
          *(short8*)(dst + j*8) = *(const short8*)(srcp + j*8);
      }
      __syncthreads();
    }
  }
}

// ---------------- fused node kernel, layers 1&2: one wave per node ----------------
// kv row = [k 0..255 | v 256..511], 1KB stride. Lane l owns channels l*4..l*4+3 of
// both k and v. 8-edge predicated blocks -> 16 independent gathers in flight.
__global__ __launch_bounds__(256) void k_attn(const unsigned short* __restrict__ qb,
                                              const unsigned short* __restrict__ kv,
                                              const unsigned short* __restrict__ xb,
                                              const int* __restrict__ rowptr,
                                              const int* __restrict__ srcs,
                                              const void* __restrict__ Wb,
                                              const void* __restrict__ lng,
                                              const void* __restrict__ lnb,
                                              unsigned short* __restrict__ hout,
                                              int N, int E, const int* __restrict__ flagp){
  int f32 = *flagp;
  int tid = threadIdx.x, w = tid >> 6, l = tid & 63;
  int n = blockIdx.x * 4 + w;
  if (n >= N) return;
  size_t base = (size_t)n * 256;
  us4 qv = *(const us4*)&qb[base + l*4];
  float q0 = b2f(qv.x), q1 = b2f(qv.y), q2 = b2f(qv.z), q3 = b2f(qv.w);
  int e0 = rowptr[n], e1 = rowptr[n+1];
  if (e0 < 0) e0 = 0;
  if (e1 > E) e1 = E;
  const float scale = 0.17677669529663687f;  // 1/sqrt(32)
  float ss = 0.f, o0 = 0.f, o1 = 0.f, o2 = 0.f, o3 = 0.f;
  for (int eb0 = e0; eb0 < e1; eb0 += 8){
    const unsigned short* kp[8];
    float valid[8];
    #pragma unroll
    for (int i = 0; i < 8; ++i){
      int ee = eb0 + i;
      int cl = (ee < e1) ? ee : (e1 - 1);
      unsigned s = (unsigned)srcs[cl]; if (s >= (unsigned)N) s = 0;
      kp[i] = &kv[(size_t)s * 512 + l*4];
      valid[i] = (ee < e1) ? 1.f : 0.f;
    }
    us4 kk[8], vv[8];
    #pragma unroll
    for (int i = 0; i < 8; ++i) kk[i] = *(const us4*)kp[i];
    #pragma unroll
    for (int i = 0; i < 8; ++i) vv[i] = *(const us4*)(kp[i] + 256);
    #pragma unroll
    for (int i = 0; i < 8; ++i){
      float p = q0*b2f(kk[i].x) + q1*b2f(kk[i].y) + q2*b2f(kk[i].z) + q3*b2f(kk[i].w);
      p += __shfl_xor(p, 1); p += __shfl_xor(p, 2); p += __shfl_xor(p, 4);
      float a = valid[i] * __expf(lclamp(p * scale));
      ss += a;
      o0 += a*b2f(vv[i].x); o1 += a*b2f(vv[i].y);
      o2 += a*b2f(vv[i].z); o3 += a*b2f(vv[i].w);
    }
  }
  float sinv = 1.f / (ss + 1e-16f);
  o0 = sane(o0 * sinv); o1 = sane(o1 * sinv);
  o2 = sane(o2 * sinv); o3 = sane(o3 * sinv);
  int c = l * 4;
  us4 xv = *(const us4*)&xb[base + c];
  float x0 = sane(b2f(xv.x)), x1 = sane(b2f(xv.y)), x2 = sane(b2f(xv.z)), x3 = sane(b2f(xv.w));
  float d = o0*ldin(Wb, c+0, f32) + x0*ldin(Wb, 256+c+0, f32) + (o0-x0)*ldin(Wb, 512+c+0, f32)
          + o1*ldin(Wb, c+1, f32) + x1*ldin(Wb, 256+c+1, f32) + (o1-x1)*ldin(Wb, 512+c+1, f32)
          + o2*ldin(Wb, c+2, f32) + x2*ldin(Wb, 256+c+2, f32) + (o2-x2)*ldin(Wb, 512+c+2, f32)
          + o3*ldin(Wb, c+3, f32) + x3*ldin(Wb, 256+c+3, f32) + (o3-x3)*ldin(Wb, 512+c+3, f32);
  #pragma unroll
  for (int off = 32; off; off >>= 1) d += __shfl_xor(d, off);
  float beta = 1.f / (1.f + __expf(-d));
  float r0 = beta*x0 + (1.f-beta)*o0;
  float r1 = beta*x1 + (1.f-beta)*o1;
  float r2 = beta*x2 + (1.f-beta)*o2;
  float r3 = beta*x3 + (1.f-beta)*o3;
  float sm = r0 + r1 + r2 + r3;
  #pragma unroll
  for (int off = 32; off; off >>= 1) sm += __shfl_xor(sm, off);
  float mu = sm * (1.f/256.f);
  float d0 = r0-mu, d1 = r1-mu, d2 = r2-mu, d3 = r3-mu;
  float vv2 = d0*d0 + d1*d1 + d2*d2 + d3*d3;
  #pragma unroll
  for (int off = 32; off; off >>= 1) vv2 += __shfl_xor(vv2, off);
  float rs = rsqrtf(vv2 * (1.f/256.f) + 1e-5f);
  us4 outv;
  outv.x = f2b(fmaxf(d0*rs*ldin(lng,c+0,f32) + ldin(lnb,c+0,f32), 0.f));
  outv.y = f2b(fmaxf(d1*rs*ldin(lng,c+1,f32) + ldin(lnb,c+1,f32), 0.f));
  outv.z = f2b(fmaxf(d2*rs*ldin(lng,c+2,f32) + ldin(lnb,c+2,f32), 0.f));
  outv.w = f2b(fmaxf(d3*rs*ldin(lng,c+3,f32) + ldin(lnb,c+3,f32), 0.f));
  *(us4*)&hout[base + c] = outv;
}

// ---------------- fused node kernel, layer 3: one wave per node, kv-packed ----------------
// kv3 row = [k 0..63 | v 64..127] (256 B). One wave-load covers 4 edges (16 lanes each).
// Within 16 lanes: t<8 -> head t's full k (8 ch); t>=8 -> head (t-8)'s full v.
__global__ __launch_bounds__(256) void k_final(const unsigned short* __restrict__ q3,
                                               const unsigned short* __restrict__ kv3,
                                               const unsigned short* __restrict__ x3,
                                               const int* __restrict__ rowptr,
                                               const int* __restrict__ srcs,
                                               const void* __restrict__ Wb,
                                               void* __restrict__ outp,
                                               int N, int E, const int* __restrict__ flagp){
  int f32 = *flagp;
  int tid = threadIdx.x, w = tid >> 6, l = tid & 63;
  int n = blockIdx.x * 4 + w;
  if (n >= N) return;
  int es = l >> 4, t = l & 15;
  size_t base = (size_t)n * 64;
  float qf[8];
  {
    short8 qv8 = *(const short8*)&q3[base + (t & 7)*8];
    #pragma unroll
    for (int j = 0; j < 8; ++j) qf[j] = b2f((unsigned short)qv8[j]);
  }
  int e0 = rowptr[n], e1 = rowptr[n+1];
  if (e0 < 0) e0 = 0;
  if (e1 > E) e1 = E;
  int deg = e1 - e0;
  const float scale = 0.35355339059327373f;  // 1/sqrt(8)
  float ss = 0.f;
  float o[8] = {0,0,0,0,0,0,0,0};
  for (int ei = es; ei < deg; ei += 4){
    unsigned s = (unsigned)srcs[e0 + ei]; if (s >= (unsigned)N) s = 0;
    short8 cA = *(const short8*)&kv3[(size_t)s*128 + t*8];
    float fA[8];
    #pragma unroll
    for (int j = 0; j < 8; ++j) fA[j] = b2f((unsigned short)cA[j]);
    float p = qf[0]*fA[0] + qf[1]*fA[1] + qf[2]*fA[2] + qf[3]*fA[3]
            + qf[4]*fA[4] + qf[5]*fA[5] + qf[6]*fA[6] + qf[7]*fA[7];
    float wA = __expf(lclamp(p * scale));
    ss += wA;
    float wv = __shfl_xor(wA, 8);   // v lanes get their head's weight
    #pragma unroll
    for (int j = 0; j < 8; ++j) o[j] += wv * fA[j];
  }
  // merge es groups
  ss += __shfl_xor(ss, 16); ss += __shfl_xor(ss, 32);
  #pragma unroll
  for (int j = 0; j < 8; ++j){ o[j] += __shfl_xor(o[j], 16); o[j] += __shfl_xor(o[j], 32); }
  // v lanes normalize by their head's denominator
  float ssu = __shfl_xor(ss, 8);
  float sinv = 1.f / (ssu + 1e-16f);
  #pragma unroll
  for (int j = 0; j < 8; ++j) o[j] = sane(o[j] * sinv);
  // mean over heads: reduce across t-8 (bits 0..2) within v lanes
  #pragma unroll
  for (int j = 0; j < 8; ++j){
    o[j] += __shfl_xor(o[j], 1); o[j] += __shfl_xor(o[j], 2); o[j] += __shfl_xor(o[j], 4);
    o[j] *= 0.125f;
  }
  float xf[8];
  {
    short8 xv8 = *(const short8*)&x3[base];
    #pragma unroll
    for (int j = 0; j < 8; ++j) xf[j] = sane(b2f((unsigned short)xv8[j]));
  }
  float d = 0.f;
  #pragma unroll
  for (int j = 0; j < 8; ++j)
    d += o[j]*ldin(Wb, j, f32) + xf[j]*ldin(Wb, 8+j, f32) + (o[j]-xf[j])*ldin(Wb, 16+j, f32);
  float beta = 1.f / (1.f + __expf(-d));
  if (l == 8){
    if (f32){
      float* op = (float*)outp + (size_t)n*8;
      #pragma unroll
      for (int j = 0; j < 8; ++j) op[j] = beta*xf[j] + (1.f-beta)*o[j];
    } else {
      short8 ov;
      #pragma unroll
      for (int j = 0; j < 8; ++j) ov[j] = (short)f2b(beta*xf[j] + (1.f-beta)*o[j]);
      *(short8*)((unsigned short*)outp + (size_t)n*8) = ov;
    }
  }
}

extern "C" void kernel_launch(void* const* d_in, const int* in_sizes, int n_in,
                              void* d_out, int out_size, void* d_ws, size_t ws_size,
                              hipStream_t stream){
  const int* ei = (const int*)d_in[1];
  const int N = in_sizes[0] / 256;
  const int E = in_sizes[1] / 2;

  char* wsp = (char*)d_ws;
  size_t off = 0;
  auto alloc = [&](size_t b) -> void* {
    void* p = wsp + off; off = (off + b + 255) & ~(size_t)255; return p;
  };
  unsigned short* WT1  = (unsigned short*)alloc((size_t)1024*256*2);
  unsigned short* WT2  = (unsigned short*)alloc((size_t)1024*256*2);
  unsigned short* WT3  = (unsigned short*)alloc((size_t)256*256*2);
  float* bias1 = (float*)alloc(1024*4);
  float* bias2 = (float*)alloc(1024*4);
  float* bias3 = (float*)alloc(256*4);
  int* flag   = (int*)alloc(256);
  int* deg    = (int*)alloc((size_t)N*4);
  int* rowptr = (int*)alloc((size_t)(N+1)*4);
  int* cursor = (int*)alloc((size_t)N*4);
  int* bsum   = (int*)alloc(1024*4);
  int* boff   = (int*)alloc(1024*4);
  int* srcs   = (int*)alloc((size_t)E*4);
  unsigned short* xbf = (unsigned short*)alloc((size_t)N*256*2);
  unsigned short* qb  = (unsigned short*)alloc((size_t)N*256*2);
  unsigned short* kv  = (unsigned short*)alloc((size_t)N*512*2);
  unsigned short* xb  = (unsigned short*)alloc((size_t)N*256*2);
  unsigned short* hbuf= (unsigned short*)alloc((size_t)N*256*2);
  unsigned short* q3  = qb;      // layer-3 aliases (then-free)
  unsigned short* kv3 = kv;
  unsigned short* x3  = xb;
  (void)ws_size; (void)n_in; (void)out_size;

  // dtype flag + canonical bf16 x
  k_flag<<<1, 256, 0, stream>>>((const unsigned short*)d_in[0], flag);
  int n4 = (N * 256) / 4;
  k_cvt<<<(n4 + 255) / 256, 256, 0, stream>>>(d_in[0], xbf, n4, flag);

  // CSR build (dst-sorted), parallel scan
  hipMemsetAsync(deg, 0, (size_t)N*4, stream);
  int eb = (E + 255) / 256;
  int nbk = (N + 1023) / 1024;
  k_deg<<<eb, 256, 0, stream>>>(ei, E, N, deg);
  k_bsum<<<nbk, 256, 0, stream>>>(deg, N, bsum);
  k_bscan<<<1, 64, 0, stream>>>(bsum, nbk, boff, rowptr, N);
  k_rowptr<<<nbk, 256, 0, stream>>>(deg, boff, N, rowptr, cursor);
  k_scatter<<<eb, 256, 0, stream>>>(ei, E, N, cursor, srcs);

  // pack transposed fused weights + biases
  k_pack<<<1024, 256, 0, stream>>>(d_in[2],  d_in[3],  d_in[4],  d_in[5],  d_in[6],  d_in[7],  d_in[8],  d_in[9],  WT1, bias1, 256, 256, 256, flag);
  k_pack<<<1024, 256, 0, stream>>>(d_in[11], d_in[12], d_in[13], d_in[14], d_in[15], d_in[16], d_in[17], d_in[18], WT2, bias2, 256, 256, 256, flag);
  k_pack<<< 256, 256, 0, stream>>>(d_in[20], d_in[21], d_in[22], d_in[23], d_in[24], d_in[25], d_in[26], d_in[27], WT3, bias3,  64,   8, 256, flag);

  int rb = (N + 63) / 64;
  int nb = (N + 3) / 4;
  // layer 1: sections q|k|v|x -> qb, kv(+0), kv(+256), xb
  k_gemm<<<rb, 256, 0, stream>>>(xbf, WT1, bias1, qb, kv, kv + 256, xb, N, 1024, 8, 256, 512, 512, 256);
  k_attn<<<nb, 256, 0, stream>>>(qb, kv, xb, rowptr, srcs, d_in[10], d_in[29], d_in[30], hbuf, N, E, flag);
  // layer 2
  k_gemm<<<rb, 256, 0, stream>>>(hbuf, WT2, bias2, qb, kv, kv + 256, xb, N, 1024, 8, 256, 512, 512, 256);
  k_attn<<<nb, 256, 0, stream>>>(qb, kv, xb, rowptr, srcs, d_in[19], d_in[31], d_in[32], hbuf, N, E, flag);
  // layer 3: sections q|k|v|x (64 each) -> q3, kv3(+0), kv3(+64), x3
  k_gemm<<<rb, 256, 0, stream>>>(hbuf, WT3, bias3, q3, kv3, kv3 + 64, x3, N, 256, 6, 64, 128, 128, 64);
  k_final<<<nb, 256, 0, stream>>>(q3, kv3, x3, rowptr, srcs, d_in[28], d_out, N, E, flag);
}

// Round 10
// 694.388 us; speedup vs baseline: 1.2923x; 1.0120x over previous
//
#include <hip/hip_runtime.h>
#include <stdint.h>

typedef __attribute__((ext_vector_type(8))) short short8;
typedef __attribute__((ext_vector_type(4))) float f32x4;

struct us4 { unsigned short x, y, z, w; };

__device__ __forceinline__ float b2f(unsigned short u){
  union { unsigned int i; float f; } x; x.i = ((unsigned int)u) << 16; return x.f;
}
__device__ __forceinline__ unsigned short f2b(float f){
  union { float f; unsigned int i; } x; x.f = f;
  unsigned int i = x.i;
  unsigned int r = (i + 0x7FFFu + ((i >> 16) & 1u)) >> 16;
  return (unsigned short)r;
}
__device__ __forceinline__ float sane(float v){
  return fminf(fmaxf(v, -1e30f), 1e30f);
}
// clamp logit: NaN -> -60, range +-60 (exp-safe; softmax invariant to shift)
__device__ __forceinline__ float lclamp(float v){
  return fminf(fmaxf(v, -60.f), 60.f);
}
__device__ __forceinline__ float ldin(const void* p, size_t i, int f32){
  return f32 ? ((const float*)p)[i] : b2f(((const unsigned short*)p)[i]);
}

// ---------------- dtype discriminator ----------------
__global__ void k_flag(const unsigned short* __restrict__ xu, int* __restrict__ flag){
  __shared__ int cnt;
  if (threadIdx.x == 0) cnt = 0;
  __syncthreads();
  unsigned u = xu[2 * threadIdx.x];
  int e = (u >> 7) & 0xFF;
  if (e >= 97 && e <= 132) atomicAdd(&cnt, 1);
  __syncthreads();
  if (threadIdx.x == 0) flag[0] = (cnt >= 192) ? 0 : 1;   // 0=bf16, 1=fp32
}

// ---------------- x -> bf16 canonical copy (vectorized) ----------------
__global__ void k_cvt(const void* __restrict__ xin, unsigned short* __restrict__ xb,
                      int n4, const int* __restrict__ flagp){
  int f32 = *flagp;
  int i = blockIdx.x * 256 + threadIdx.x;
  if (i < n4){
    if (f32){
      float4 v = ((const float4*)xin)[i];
      us4 o = { f2b(v.x), f2b(v.y), f2b(v.z), f2b(v.w) };
      ((us4*)xb)[i] = o;
    } else {
      ((us4*)xb)[i] = ((const us4*)xin)[i];
    }
  }
}

// ---------------- CSR build (parallel scan) ----------------
__global__ void k_deg(const int* __restrict__ ei, int E, int N, int* __restrict__ deg){
  int e = blockIdx.x * 256 + threadIdx.x;
  if (e < E){
    unsigned d = (unsigned)ei[E + e];
    if (d < (unsigned)N) atomicAdd(&deg[d], 1);
  }
}

__global__ void k_bsum(const int* __restrict__ deg, int N, int* __restrict__ bsum){
  int b = blockIdx.x, t = threadIdx.x;
  int i0 = b * 1024 + t * 4;
  int s = 0;
  if (i0 + 4 <= N){
    int4 v = *(const int4*)&deg[i0];
    s = v.x + v.y + v.z + v.w;
  } else {
    #pragma unroll
    for (int j = 0; j < 4; ++j){ int i = i0 + j; if (i < N) s += deg[i]; }
  }
  #pragma unroll
  for (int off = 32; off; off >>= 1) s += __shfl_xor(s, off);
  __shared__ int ws[4];
  if ((t & 63) == 0) ws[t >> 6] = s;
  __syncthreads();
  if (t == 0) bsum[b] = ws[0] + ws[1] + ws[2] + ws[3];
}

__global__ void k_bscan(const int* __restrict__ bsum, int nb,
                        int* __restrict__ boff, int* __restrict__ rowptr, int N){
  int t = threadIdx.x;
  if (nb <= 64){
    int v = (t < nb) ? bsum[t] : 0;
    int inc = v;
    #pragma unroll
    for (int off = 1; off < 64; off <<= 1){
      int u = __shfl_up(inc, off);
      if (t >= off) inc += u;
    }
    if (t < nb) boff[t] = inc - v;
    if (t == 63) rowptr[N] = inc;
  } else {
    if (t == 0){
      int run = 0;
      for (int i = 0; i < nb; ++i){ boff[i] = run; run += bsum[i]; }
      rowptr[N] = run;
    }
  }
}

__global__ void k_rowptr(const int* __restrict__ deg, const int* __restrict__ boff,
                         int N, int* __restrict__ rowptr, int* __restrict__ cursor){
  int b = blockIdx.x, t = threadIdx.x;
  int i0 = b * 1024 + t * 4;
  int d0 = 0, d1 = 0, d2 = 0, d3 = 0;
  if (i0 + 4 <= N){
    int4 v = *(const int4*)&deg[i0];
    d0 = v.x; d1 = v.y; d2 = v.z; d3 = v.w;
  } else {
    if (i0     < N) d0 = deg[i0];
    if (i0 + 1 < N) d1 = deg[i0 + 1];
    if (i0 + 2 < N) d2 = deg[i0 + 2];
    if (i0 + 3 < N) d3 = deg[i0 + 3];
  }
  int s = d0 + d1 + d2 + d3;
  int lane = t & 63, w = t >> 6;
  int inc = s;
  #pragma unroll
  for (int off = 1; off < 64; off <<= 1){
    int u = __shfl_up(inc, off);
    if (lane >= off) inc += u;
  }
  int wex = inc - s;
  __shared__ int wtot[4];
  if (lane == 63) wtot[w] = inc;
  __syncthreads();
  int cross = 0;
  for (int i = 0; i < w; ++i) cross += wtot[i];
  int basev = boff[b] + cross + wex;
  int r0 = basev, r1 = basev + d0, r2 = r1 + d1, r3 = r2 + d2;
  if (i0 + 4 <= N){
    int4 o = { r0, r1, r2, r3 };
    *(int4*)&rowptr[i0] = o;
    *(int4*)&cursor[i0] = o;
  } else {
    if (i0     < N){ rowptr[i0]   = r0; cursor[i0]   = r0; }
    if (i0 + 1 < N){ rowptr[i0+1] = r1; cursor[i0+1] = r1; }
    if (i0 + 2 < N){ rowptr[i0+2] = r2; cursor[i0+2] = r2; }
    if (i0 + 3 < N){ rowptr[i0+3] = r3; cursor[i0+3] = r3; }
  }
}

__global__ void k_scatter(const int* __restrict__ ei, int E, int N,
                          int* __restrict__ cursor, int* __restrict__ srcs){
  int e = blockIdx.x * 256 + threadIdx.x;
  if (e < E){
    unsigned d = (unsigned)ei[E + e];
    if (d < (unsigned)N){
      int pos = atomicAdd(&cursor[d], 1);
      if ((unsigned)pos < (unsigned)E){
        unsigned s = (unsigned)ei[e];
        srcs[pos] = (s < (unsigned)N) ? (int)s : 0;
      }
    }
  }
}

// ---------------- weight pack: WT[cg][k] = W_mat[k][c] (bf16), bias as float ----------------
__global__ void k_pack(const void* __restrict__ Wq, const void* __restrict__ bq,
                       const void* __restrict__ Wk, const void* __restrict__ bk,
                       const void* __restrict__ Wv, const void* __restrict__ bv,
                       const void* __restrict__ Ws, const void* __restrict__ bs,
                       unsigned short* __restrict__ WT, float* __restrict__ bias,
                       int Mq, int Ms, int K, const int* __restrict__ flagp){
  int f32 = *flagp;
  int cg = blockIdx.x;
  int k  = threadIdx.x;
  int mat, c, mc;
  if (cg < 3 * Mq){ mat = cg / Mq; c = cg % Mq; mc = Mq; }
  else if (cg < 3 * Mq + Ms){ mat = 3; c = cg - 3 * Mq; mc = Ms; }
  else { mat = 4; c = 0; mc = 1; }
  const void* W = (mat==0)?Wq:(mat==1)?Wk:(mat==2)?Wv:(mat==3)?Ws:(const void*)0;
  WT[(size_t)cg * K + k] = (mat < 4) ? f2b(ldin(W, (size_t)k * mc + c, f32)) : (unsigned short)0;
  if (k == 0){
    const void* B = (mat==0)?bq:(mat==1)?bk:(mat==2)?bv:(mat==3)?bs:(const void*)0;
    bias[cg] = (mat < 4) ? ldin(B, c, f32) : 0.f;
  }
}

// ---------------- GEMM: split-output (per-section stride), coalesced LDS epilogue ----------------
__global__ __launch_bounds__(256) void k_gemm(const unsigned short* __restrict__ A,
                                              const unsigned short* __restrict__ WT,
                                              const float* __restrict__ bias,
                                              unsigned short* __restrict__ B0,
                                              unsigned short* __restrict__ B1,
                                              unsigned short* __restrict__ B2,
                                              unsigned short* __restrict__ B3,
                                              int N, int Mout, int secshift,
                                              int st0, int st1, int st2, int st3){
  __shared__ __align__(16) unsigned short Alds[64][264];
  __shared__ __align__(16) unsigned short Clds[32][276];
  int tid = threadIdx.x, wid = tid >> 6, lane = tid & 63;
  int l15 = lane & 15, l4 = lane >> 4;
  int row0 = blockIdx.x * 64;
  {
    int srow = tid >> 2, sc4 = tid & 3;
    int ar = row0 + srow; if (ar >= N) ar = N - 1;
    const unsigned short* Ap = A + (size_t)ar * 256;
    #pragma unroll
    for (int i = 0; i < 8; ++i){
      int col = (sc4 + 4 * i) * 8;
      *(short8*)&Alds[srow][col] = *(const short8*)&Ap[col];
    }
  }
  __syncthreads();
  int secw = 1 << secshift;
  int strow = tid >> 3, stchunk = tid & 7;
  for (int cb = wid * 64; cb < Mout; cb += 256){
    f32x4 acc[4][4] = {};
    #pragma unroll
    for (int k0 = 0; k0 < 256; k0 += 32){
      short8 a0 = *(const short8*)&Alds[l15     ][k0 + l4*8];
      short8 a1 = *(const short8*)&Alds[16 + l15][k0 + l4*8];
      short8 a2 = *(const short8*)&Alds[32 + l15][k0 + l4*8];
      short8 a3 = *(const short8*)&Alds[48 + l15][k0 + l4*8];
      const unsigned short* wb = WT + (size_t)(cb + l15) * 256 + k0 + l4*8;
      short8 b0 = *(const short8*)(wb);
      short8 b1 = *(const short8*)(wb + 16*256);
      short8 b2 = *(const short8*)(wb + 32*256);
      short8 b3 = *(const short8*)(wb + 48*256);
      acc[0][0] = __builtin_amdgcn_mfma_f32_16x16x32_bf16(a0, b0, acc[0][0], 0,0,0);
      acc[0][1] = __builtin_amdgcn_mfma_f32_16x16x32_bf16(a0, b1, acc[0][1], 0,0,0);
      acc[0][2] = __builtin_amdgcn_mfma_f32_16x16x32_bf16(a0, b2, acc[0][2], 0,0,0);
      acc[0][3] = __builtin_amdgcn_mfma_f32_16x16x32_bf16(a0, b3, acc[0][3], 0,0,0);
      acc[1][0] = __builtin_amdgcn_mfma_f32_16x16x32_bf16(a1, b0, acc[1][0], 0,0,0);
      acc[1][1] = __builtin_amdgcn_mfma_f32_16x16x32_bf16(a1, b1, acc[1][1], 0,0,0);
      acc[1][2] = __builtin_amdgcn_mfma_f32_16x16x32_bf16(a1, b2, acc[1][2], 0,0,0);
      acc[1][3] = __builtin_amdgcn_mfma_f32_16x16x32_bf16(a1, b3, acc[1][3], 0,0,0);
      acc[2][0] = __builtin_amdgcn_mfma_f32_16x16x32_bf16(a2, b0, acc[2][0], 0,0,0);
      acc[2][1] = __builtin_amdgcn_mfma_f32_16x16x32_bf16(a2, b1, acc[2][1], 0,0,0);
      acc[2][2] = __builtin_amdgcn_mfma_f32_16x16x32_bf16(a2, b2, acc[2][2], 0,0,0);
      acc[2][3] = __builtin_amdgcn_mfma_f32_16x16x32_bf16(a2, b3, acc[2][3], 0,0,0);
      acc[3][0] = __builtin_amdgcn_mfma_f32_16x16x32_bf16(a3, b0, acc[3][0], 0,0,0);
      acc[3][1] = __builtin_amdgcn_mfma_f32_16x16x32_bf16(a3, b1, acc[3][1], 0,0,0);
      acc[3][2] = __builtin_amdgcn_mfma_f32_16x16x32_bf16(a3, b2, acc[3][2], 0,0,0);
      acc[3][3] = __builtin_amdgcn_mfma_f32_16x16x32_bf16(a3, b3, acc[3][3], 0,0,0);
    }
    int gb = cb - wid * 64;
    #pragma unroll
    for (int ph = 0; ph < 2; ++ph){
      #pragma unroll
      for (int rt2 = 0; rt2 < 2; ++rt2){
        int rt = ph*2 + rt2;
        #pragma unroll
        for (int ct = 0; ct < 4; ++ct){
          float bv = bias[cb + ct*16 + l15];
          #pragma unroll
          for (int r = 0; r < 4; ++r)
            Clds[rt2*16 + l4*4 + r][wid*64 + ct*16 + l15] = f2b(acc[rt][ct][r] + bv);
        }
      }
      __syncthreads();
      int grow = row0 + ph*32 + strow;
      if (grow < N){
        int g0 = gb + stchunk * 32;
        int mat = g0 >> secshift;
        int cc  = g0 & (secw - 1);
        unsigned short* Bp = (mat==0)?B0:(mat==1)?B1:(mat==2)?B2:B3;
        int stw = (mat==0)?st0:(mat==1)?st1:(mat==2)?st2:st3;
        unsigned short* dst = Bp + (size_t)grow * stw + cc;
        const unsigned short* srcp = &Clds[strow][stchunk * 32];
        #pragma unroll
        for (int j = 0; j < 4; ++j)
          *(short8*)(dst + j*8) = *(const short8*)(srcp + j*8);
      }
      __syncthreads();
    }
  }
}

// ---------------- fused node kernel, layers 1&2: one wave per node ----------------
// kv row = [k 0..255 | v 256..511], 1KB stride. 8 predicated edges per iteration,
// all loads in NAMED variables (no arrays -> no spill/serialize) -> 16 gathers in flight.
#define EDGE_DECL(i) \
    int ce##i = eb0 + i; int cl##i = (ce##i < e1) ? ce##i : last; \
    unsigned s##i = (unsigned)srcs[cl##i]; if (s##i >= (unsigned)N) s##i = 0; \
    const unsigned short* p##i = kvl + (size_t)s##i * 512; \
    float m##i = (ce##i < e1) ? 1.f : 0.f;
#define EDGE_LOADK(i) us4 k##i = *(const us4*)p##i;
#define EDGE_LOADV(i) us4 v##i = *(const us4*)(p##i + 256);
#define EDGE_COMP(i) { \
    float p = q0*b2f(k##i.x) + q1*b2f(k##i.y) + q2*b2f(k##i.z) + q3*b2f(k##i.w); \
    p += __shfl_xor(p, 1); p += __shfl_xor(p, 2); p += __shfl_xor(p, 4); \
    float a = m##i * __expf(lclamp(p * scale)); \
    ss += a; \
    o0 += a*b2f(v##i.x); o1 += a*b2f(v##i.y); o2 += a*b2f(v##i.z); o3 += a*b2f(v##i.w); }

__global__ __launch_bounds__(256) void k_attn(const unsigned short* __restrict__ qb,
                                              const unsigned short* __restrict__ kv,
                                              const unsigned short* __restrict__ xb,
                                              const int* __restrict__ rowptr,
                                              const int* __restrict__ srcs,
                                              const void* __restrict__ Wb,
                                              const void* __restrict__ lng,
                                              const void* __restrict__ lnb,
                                              unsigned short* __restrict__ hout,
                                              int N, int E, const int* __restrict__ flagp){
  int f32 = *flagp;
  int tid = threadIdx.x, w = tid >> 6, l = tid & 63;
  int n = blockIdx.x * 4 + w;
  if (n >= N) return;
  size_t base = (size_t)n * 256;
  us4 qv = *(const us4*)&qb[base + l*4];
  float q0 = b2f(qv.x), q1 = b2f(qv.y), q2 = b2f(qv.z), q3 = b2f(qv.w);
  int e0 = rowptr[n], e1 = rowptr[n+1];
  if (e0 < 0) e0 = 0;
  if (e1 > E) e1 = E;
  int last = e1 - 1;
  const unsigned short* kvl = kv + l*4;
  const float scale = 0.17677669529663687f;  // 1/sqrt(32)
  float ss = 0.f, o0 = 0.f, o1 = 0.f, o2 = 0.f, o3 = 0.f;
  for (int eb0 = e0; eb0 < e1; eb0 += 8){
    EDGE_DECL(0) EDGE_DECL(1) EDGE_DECL(2) EDGE_DECL(3)
    EDGE_DECL(4) EDGE_DECL(5) EDGE_DECL(6) EDGE_DECL(7)
    EDGE_LOADK(0) EDGE_LOADK(1) EDGE_LOADK(2) EDGE_LOADK(3)
    EDGE_LOADK(4) EDGE_LOADK(5) EDGE_LOADK(6) EDGE_LOADK(7)
    EDGE_LOADV(0) EDGE_LOADV(1) EDGE_LOADV(2) EDGE_LOADV(3)
    EDGE_LOADV(4) EDGE_LOADV(5) EDGE_LOADV(6) EDGE_LOADV(7)
    EDGE_COMP(0) EDGE_COMP(1) EDGE_COMP(2) EDGE_COMP(3)
    EDGE_COMP(4) EDGE_COMP(5) EDGE_COMP(6) EDGE_COMP(7)
  }
  float sinv = 1.f / (ss + 1e-16f);
  o0 = sane(o0 * sinv); o1 = sane(o1 * sinv);
  o2 = sane(o2 * sinv); o3 = sane(o3 * sinv);
  int c = l * 4;
  us4 xv = *(const us4*)&xb[base + c];
  float x0 = sane(b2f(xv.x)), x1 = sane(b2f(xv.y)), x2 = sane(b2f(xv.z)), x3 = sane(b2f(xv.w));
  float d = o0*ldin(Wb, c+0, f32) + x0*ldin(Wb, 256+c+0, f32) + (o0-x0)*ldin(Wb, 512+c+0, f32)
          + o1*ldin(Wb, c+1, f32) + x1*ldin(Wb, 256+c+1, f32) + (o1-x1)*ldin(Wb, 512+c+1, f32)
          + o2*ldin(Wb, c+2, f32) + x2*ldin(Wb, 256+c+2, f32) + (o2-x2)*ldin(Wb, 512+c+2, f32)
          + o3*ldin(Wb, c+3, f32) + x3*ldin(Wb, 256+c+3, f32) + (o3-x3)*ldin(Wb, 512+c+3, f32);
  #pragma unroll
  for (int off = 32; off; off >>= 1) d += __shfl_xor(d, off);
  float beta = 1.f / (1.f + __expf(-d));
  float r0 = beta*x0 + (1.f-beta)*o0;
  float r1 = beta*x1 + (1.f-beta)*o1;
  float r2 = beta*x2 + (1.f-beta)*o2;
  float r3 = beta*x3 + (1.f-beta)*o3;
  float sm = r0 + r1 + r2 + r3;
  #pragma unroll
  for (int off = 32; off; off >>= 1) sm += __shfl_xor(sm, off);
  float mu = sm * (1.f/256.f);
  float d0 = r0-mu, d1 = r1-mu, d2 = r2-mu, d3 = r3-mu;
  float vv2 = d0*d0 + d1*d1 + d2*d2 + d3*d3;
  #pragma unroll
  for (int off = 32; off; off >>= 1) vv2 += __shfl_xor(vv2, off);
  float rs = rsqrtf(vv2 * (1.f/256.f) + 1e-5f);
  us4 outv;
  outv.x = f2b(fmaxf(d0*rs*ldin(lng,c+0,f32) + ldin(lnb,c+0,f32), 0.f));
  outv.y = f2b(fmaxf(d1*rs*ldin(lng,c+1,f32) + ldin(lnb,c+1,f32), 0.f));
  outv.z = f2b(fmaxf(d2*rs*ldin(lng,c+2,f32) + ldin(lnb,c+2,f32), 0.f));
  outv.w = f2b(fmaxf(d3*rs*ldin(lng,c+3,f32) + ldin(lnb,c+3,f32), 0.f));
  *(us4*)&hout[base + c] = outv;
}

// ---------------- fused node kernel, layer 3: one wave per node, kv-packed ----------------
__global__ __launch_bounds__(256) void k_final(const unsigned short* __restrict__ q3,
                                               const unsigned short* __restrict__ kv3,
                                               const unsigned short* __restrict__ x3,
                                               const int* __restrict__ rowptr,
                                               const int* __restrict__ srcs,
                                               const void* __restrict__ Wb,
                                               void* __restrict__ outp,
                                               int N, int E, const int* __restrict__ flagp){
  int f32 = *flagp;
  int tid = threadIdx.x, w = tid >> 6, l = tid & 63;
  int n = blockIdx.x * 4 + w;
  if (n >= N) return;
  int es = l >> 4, t = l & 15;
  size_t base = (size_t)n * 64;
  float qf[8];
  {
    short8 qv8 = *(const short8*)&q3[base + (t & 7)*8];
    #pragma unroll
    for (int j = 0; j < 8; ++j) qf[j] = b2f((unsigned short)qv8[j]);
  }
  int e0 = rowptr[n], e1 = rowptr[n+1];
  if (e0 < 0) e0 = 0;
  if (e1 > E) e1 = E;
  int deg = e1 - e0;
  const float scale = 0.35355339059327373f;  // 1/sqrt(8)
  float ss = 0.f;
  float o[8] = {0,0,0,0,0,0,0,0};
  for (int ei = es; ei < deg; ei += 4){
    unsigned s = (unsigned)srcs[e0 + ei]; if (s >= (unsigned)N) s = 0;
    short8 cA = *(const short8*)&kv3[(size_t)s*128 + t*8];
    float fA[8];
    #pragma unroll
    for (int j = 0; j < 8; ++j) fA[j] = b2f((unsigned short)cA[j]);
    float p = qf[0]*fA[0] + qf[1]*fA[1] + qf[2]*fA[2] + qf[3]*fA[3]
            + qf[4]*fA[4] + qf[5]*fA[5] + qf[6]*fA[6] + qf[7]*fA[7];
    float wA = __expf(lclamp(p * scale));
    ss += wA;
    float wv = __shfl_xor(wA, 8);   // v lanes get their head's weight
    #pragma unroll
    for (int j = 0; j < 8; ++j) o[j] += wv * fA[j];
  }
  ss += __shfl_xor(ss, 16); ss += __shfl_xor(ss, 32);
  #pragma unroll
  for (int j = 0; j < 8; ++j){ o[j] += __shfl_xor(o[j], 16); o[j] += __shfl_xor(o[j], 32); }
  float ssu = __shfl_xor(ss, 8);
  float sinv = 1.f / (ssu + 1e-16f);
  #pragma unroll
  for (int j = 0; j < 8; ++j) o[j] = sane(o[j] * sinv);
  #pragma unroll
  for (int j = 0; j < 8; ++j){
    o[j] += __shfl_xor(o[j], 1); o[j] += __shfl_xor(o[j], 2); o[j] += __shfl_xor(o[j], 4);
    o[j] *= 0.125f;
  }
  float xf[8];
  {
    short8 xv8 = *(const short8*)&x3[base];
    #pragma unroll
    for (int j = 0; j < 8; ++j) xf[j] = sane(b2f((unsigned short)xv8[j]));
  }
  float d = 0.f;
  #pragma unroll
  for (int j = 0; j < 8; ++j)
    d += o[j]*ldin(Wb, j, f32) + xf[j]*ldin(Wb, 8+j, f32) + (o[j]-xf[j])*ldin(Wb, 16+j, f32);
  float beta = 1.f / (1.f + __expf(-d));
  if (l == 8){
    if (f32){
      float* op = (float*)outp + (size_t)n*8;
      #pragma unroll
      for (int j = 0; j < 8; ++j) op[j] = beta*xf[j] + (1.f-beta)*o[j];
    } else {
      short8 ov;
      #pragma unroll
      for (int j = 0; j < 8; ++j) ov[j] = (short)f2b(beta*xf[j] + (1.f-beta)*o[j]);
      *(short8*)((unsigned short*)outp + (size_t)n*8) = ov;
    }
  }
}

extern "C" void kernel_launch(void* const* d_in, const int* in_sizes, int n_in,
                              void* d_out, int out_size, void* d_ws, size_t ws_size,
                              hipStream_t stream){
  const int* ei = (const int*)d_in[1];
  const int N = in_sizes[0] / 256;
  const int E = in_sizes[1] / 2;

  char* wsp = (char*)d_ws;
  size_t off = 0;
  auto alloc = [&](size_t b) -> void* {
    void* p = wsp + off; off = (off + b + 255) & ~(size_t)255; return p;
  };
  unsigned short* WT1  = (unsigned short*)alloc((size_t)1024*256*2);
  unsigned short* WT2  = (unsigned short*)alloc((size_t)1024*256*2);
  unsigned short* WT3  = (unsigned short*)alloc((size_t)256*256*2);
  float* bias1 = (float*)alloc(1024*4);
  float* bias2 = (float*)alloc(1024*4);
  float* bias3 = (float*)alloc(256*4);
  int* flag   = (int*)alloc(256);
  int* deg    = (int*)alloc((size_t)N*4);
  int* rowptr = (int*)alloc((size_t)(N+1)*4);
  int* cursor = (int*)alloc((size_t)N*4);
  int* bsum   = (int*)alloc(1024*4);
  int* boff   = (int*)alloc(1024*4);
  int* srcs   = (int*)alloc((size_t)E*4);
  unsigned short* xbf = (unsigned short*)alloc((size_t)N*256*2);
  unsigned short* qb  = (unsigned short*)alloc((size_t)N*256*2);
  unsigned short* kv  = (unsigned short*)alloc((size_t)N*512*2);
  unsigned short* xb  = (unsigned short*)alloc((size_t)N*256*2);
  unsigned short* hbuf= (unsigned short*)alloc((size_t)N*256*2);
  unsigned short* q3  = qb;      // layer-3 aliases (then-free)
  unsigned short* kv3 = kv;
  unsigned short* x3  = xb;
  (void)ws_size; (void)n_in; (void)out_size;

  // dtype flag + canonical bf16 x
  k_flag<<<1, 256, 0, stream>>>((const unsigned short*)d_in[0], flag);
  int n4 = (N * 256) / 4;
  k_cvt<<<(n4 + 255) / 256, 256, 0, stream>>>(d_in[0], xbf, n4, flag);

  // CSR build (dst-sorted), parallel scan
  hipMemsetAsync(deg, 0, (size_t)N*4, stream);
  int eb = (E + 255) / 256;
  int nbk = (N + 1023) / 1024;
  k_deg<<<eb, 256, 0, stream>>>(ei, E, N, deg);
  k_bsum<<<nbk, 256, 0, stream>>>(deg, N, bsum);
  k_bscan<<<1, 64, 0, stream>>>(bsum, nbk, boff, rowptr, N);
  k_rowptr<<<nbk, 256, 0, stream>>>(deg, boff, N, rowptr, cursor);
  k_scatter<<<eb, 256, 0, stream>>>(ei, E, N, cursor, srcs);

  // pack transposed fused weights + biases
  k_pack<<<1024, 256, 0, stream>>>(d_in[2],  d_in[3],  d_in[4],  d_in[5],  d_in[6],  d_in[7],  d_in[8],  d_in[9],  WT1, bias1, 256, 256, 256, flag);
  k_pack<<<1024, 256, 0, stream>>>(d_in[11], d_in[12], d_in[13], d_in[14], d_in[15], d_in[16], d_in[17], d_in[18], WT2, bias2, 256, 256, 256, flag);
  k_pack<<< 256, 256, 0, stream>>>(d_in[20], d_in[21], d_in[22], d_in[23], d_in[24], d_in[25], d_in[26], d_in[27], WT3, bias3,  64,   8, 256, flag);

  int rb = (N + 63) / 64;
  int nb = (N + 3) / 4;
  // layer 1: sections q|k|v|x -> qb, kv(+0), kv(+256), xb
  k_gemm<<<rb, 256, 0, stream>>>(xbf, WT1, bias1, qb, kv, kv + 256, xb, N, 1024, 8, 256, 512, 512, 256);
  k_attn<<<nb, 256, 0, stream>>>(qb, kv, xb, rowptr, srcs, d_in[10], d_in[29], d_in[30], hbuf, N, E, flag);
  // layer 2
  k_gemm<<<rb, 256, 0, stream>>>(hbuf, WT2, bias2, qb, kv, kv + 256, xb, N, 1024, 8, 256, 512, 512, 256);
  k_attn<<<nb, 256, 0, stream>>>(qb, kv, xb, rowptr, srcs, d_in[19], d_in[31], d_in[32], hbuf, N, E, flag);
  // layer 3: sections q|k|v|x (64 each) -> q3, kv3(+0), kv3(+64), x3
  k_gemm<<<rb, 256, 0, stream>>>(hbuf, WT3, bias3, q3, kv3, kv3 + 64, x3, N, 256, 6, 64, 128, 128, 64);
  k_final<<<nb, 256, 0, stream>>>(q3, kv3, x3, rowptr, srcs, d_in[28], d_out, N, E, flag);
}